// Round 8
// baseline (417.027 us; speedup 1.0000x reference)
//
#include <hip/hip_runtime.h>
#include <stdint.h>

typedef int int32x4  __attribute__((ext_vector_type(4)));
typedef int int32x16 __attribute__((ext_vector_type(16)));

#define IN_F   4096
#define OUT_F  4096
#define ROWS   8192   /* 4 * 2048 */

#define BM 256
#define BN 256
#define BK 64
#define NT (IN_F / BK)           /* 64 K-tiles */
#define ABUF 16384               /* A tile: 256x64 i8 = 16 KB */
#define LDS_TOTAL (4 * ABUF)     /* quad buffer = 64 KB */

// async global->LDS, 16B per lane; LDS dest must be lane-contiguous (m104/m108)
#define GLOAD_LDS16(g, l)                                                      \
  __builtin_amdgcn_global_load_lds(                                            \
      (const __attribute__((address_space(1))) void*)(g),                      \
      (__attribute__((address_space(3))) void*)(l), 16, 0, 0)

__device__ __forceinline__ int pack4i(int a, int b, int c, int d) {
  return (a & 0xff) | ((b & 0xff) << 8) | ((c & 0xff) << 16) | (d << 24);
}

// ---- cvt: int32->int8 (x) and fp32->int8 (w), BOTH into MFMA-native packed
// layout (flatmm trick): 16B chunk (eb, kb, l) at byte (eb*128 + kb)*1024 +
// l*16, where eb = row>>5, kb = k>>5, and lane l holds row (eb*32 + (l&31)),
// k bytes kb*32 + (l>>5)*16 .. +16.  A wave's MFMA fragment load is then ONE
// contiguous 1024B global/LDS read.  Thread: 32 k-values of one row (reads
// 128 B contiguous = full lines; writes 2 x 16B, per-32-thread-contiguous).
#define CVT_BLOCKS 2048
#define CVT_NA 1048576   /* 8192*4096/32 */
#define CVT_NTOT 1572864 /* + 4096*4096/32 */
__global__ void __launch_bounds__(256) cvt_kernel(const int4* __restrict__ x,
                                                  const float4* __restrict__ w,
                                                  int4* __restrict__ oa,
                                                  int4* __restrict__ ob) {
  for (size_t c = (size_t)blockIdx.x * 256 + threadIdx.x; c < CVT_NTOT;
       c += (size_t)CVT_BLOCKS * 256) {
    if (c < CVT_NA) {                    // boundary % 256 == 0: wave-uniform
      const int block = (int)(c >> 5), r = (int)(c & 31);
      const int m = (block >> 7) * 32 + r, kb = block & 127;
      const int4* src = x + (size_t)m * 1024 + kb * 8;
      int p[8];
#pragma unroll
      for (int j = 0; j < 8; ++j) {
        int4 a = src[j];
        p[j] = pack4i(a.x, a.y, a.z, a.w);
      }
      oa[(size_t)block * 64 + r]      = make_int4(p[0], p[1], p[2], p[3]);
      oa[(size_t)block * 64 + r + 32] = make_int4(p[4], p[5], p[6], p[7]);
    } else {
      const size_t c2 = c - CVT_NA;
      const int block = (int)(c2 >> 5), r = (int)(c2 & 31);
      const int n = (block >> 7) * 32 + r, kb = block & 127;
      const float4* src = w + (size_t)n * 1024 + kb * 8;
      int p[8];
#pragma unroll
      for (int j = 0; j < 8; ++j) {
        float4 a = src[j];
        p[j] = pack4i(__float2int_rn(a.x), __float2int_rn(a.y),
                      __float2int_rn(a.z), __float2int_rn(a.w));
      }
      ob[(size_t)block * 64 + r]      = make_int4(p[0], p[1], p[2], p[3]);
      ob[(size_t)block * 64 + r + 32] = make_int4(p[4], p[5], p[6], p[7]);
    }
  }
}

// ---- i8 MFMA GEMM on packed operands ---------------------------------------
// r7 post-mortem: conflicts=0 yet SLOWER -> LDS *traffic* (96KB rd + 32KB wr
// per CU-tile ~= the 1170-cyc MFMA wall) serialized with MFMA under barrier
// lockstep was the limiter, not conflicts/vmcnt/ordering.  This version cuts
// the traffic: B fragments load GLOBAL->REG directly from the packed layout
// (coalesced 1024B/instr, dup only 2x, L2-resident via bn-major XCD map); A
// stays LDS-staged (4x dedup) with packed-linear DMA and contiguous-1024B
// fragment reads.  LDS/tile: 64KB rd + 16KB wr ~= 625 cyc << 1170 MFMA.
// One barrier/tile; counted vmcnt(2) gate; issue order B-then-A so the gate
// completes A(t+1)+B(t+1) but never drains the A(t+2) prefetch.
// 8 waves (2 wm x 4 wn), per-wave 128x64 via 4x2 of mfma_i32_32x32x32_i8;
// acc=128 regs -> 2 waves/SIMD, 1 block/CU (r5 lesson: never cap below acc).
// Fragment maps (harness-verified): A/B: m|n = lane&31, k-bytes (lane>>5)*16;
// C/D: col = lane&31, row = (reg&3) + 8*(reg>>2) + 4*(lane>>5).
__global__ void __launch_bounds__(512) gemm_i8_kernel(
    const int8_t* __restrict__ A8p, const int8_t* __restrict__ B8p,
    const float* __restrict__ bias, const float* __restrict__ alpha_p,
    int* __restrict__ out) {
  extern __shared__ int8_t lds[];

  const int t    = threadIdx.x;
  const int wave = t >> 6;
  const int lane = t & 63;
  const int l31  = lane & 31;
  const int hi   = lane >> 5;
  const int wm   = wave >> 2;   // 0..1
  const int wn   = wave & 3;    // 0..3

  // XCD swizzle, bn-major within XCD: each XCD owns 2 bn-panels (2 MB of
  // packed B -> L2-resident) x all 32 bm.
  const int flat = blockIdx.y * gridDim.x + blockIdx.x;  // 0..511
  const int wid  = (flat & 7) * 64 + (flat >> 3);
  const int bn   = wid >> 5;    // 0..15
  const int bm   = wid & 31;    // 0..31

  // A DMA: thread t stages chunks cc = j*512+t (j=0,1): mb_i = j*4+(t>>7),
  // kb_i = (t>>6)&1, l = t&63.  Packed src chunk (bm*8+mb_i, tile*2+kb_i, l).
  const int mb0 = bm * 8 + (t >> 7);
  const int kbi = (t >> 6) & 1;
  const size_t aOff0 = ((size_t)mb0 * 128 + kbi) * 1024 + (size_t)(t & 63) * 16;
  const size_t aOff1 = ((size_t)(mb0 + 4) * 128 + kbi) * 1024 + (size_t)(t & 63) * 16;
  const int ldsT = t * 16;

  // B direct: frag (ni, ks) of tile T at (bn*8 + wn*2 + ni)*131072 +
  // (T*2 + ks)*1024 + lane*16  (lanes contiguous 1024B).
  const int8_t* bPtr = B8p + (size_t)(bn * 8 + wn * 2) * 131072 + (size_t)lane * 16;

  // A frag read: buf + wm*8192 + (mi*2+ks)*1024 + lane*16 (contiguous 1024B).
  const int aLds = wm * 8192 + lane * 16;

  int32x16 acc[4][2] = {};
  int32x4 af[4][2];
  int32x4 Bc00, Bc01, Bc10, Bc11, Bn00, Bn01, Bn10, Bn11;

#define ISSUE_A(TILE)                                                          \
  do {                                                                         \
    int8_t* _b = lds + ((TILE) & 3) * ABUF;                                    \
    GLOAD_LDS16(A8p + aOff0 + (size_t)(TILE) * 2048, _b + ldsT);               \
    GLOAD_LDS16(A8p + aOff1 + (size_t)(TILE) * 2048, _b + 8192 + ldsT);        \
  } while (0)

#define LOAD_B(TILE, B00, B01, B10, B11)                                       \
  do {                                                                         \
    const int8_t* _p = bPtr + (size_t)(TILE) * 2048;                           \
    B00 = *(const int32x4*)(_p);                                               \
    B01 = *(const int32x4*)(_p + 1024);                                        \
    B10 = *(const int32x4*)(_p + 131072);                                      \
    B11 = *(const int32x4*)(_p + 131072 + 1024);                               \
  } while (0)

#define READ_A(TILE)                                                           \
  do {                                                                         \
    const int8_t* _a = lds + ((TILE) & 3) * ABUF + aLds;                       \
    _Pragma("unroll") for (int mi = 0; mi < 4; ++mi) {                         \
      af[mi][0] = *(const int32x4*)(_a + mi * 2048);                           \
      af[mi][1] = *(const int32x4*)(_a + mi * 2048 + 1024);                    \
    }                                                                          \
  } while (0)

#define MFMA16(B00, B01, B10, B11)                                             \
  do {                                                                         \
    __builtin_amdgcn_s_setprio(1);                                             \
    _Pragma("unroll") for (int mi = 0; mi < 4; ++mi) {                         \
      acc[mi][0] = __builtin_amdgcn_mfma_i32_32x32x32_i8(af[mi][0], B00,       \
                                                         acc[mi][0], 0, 0, 0); \
      acc[mi][1] = __builtin_amdgcn_mfma_i32_32x32x32_i8(af[mi][0], B10,       \
                                                         acc[mi][1], 0, 0, 0); \
    }                                                                          \
    _Pragma("unroll") for (int mi = 0; mi < 4; ++mi) {                         \
      acc[mi][0] = __builtin_amdgcn_mfma_i32_32x32x32_i8(af[mi][1], B01,       \
                                                         acc[mi][0], 0, 0, 0); \
      acc[mi][1] = __builtin_amdgcn_mfma_i32_32x32x32_i8(af[mi][1], B11,       \
                                                         acc[mi][1], 0, 0, 0); \
    }                                                                          \
    __builtin_amdgcn_s_setprio(0);                                             \
  } while (0)

// gate: completes A(t+1)+B(t+1) (the 6 oldest), leaves A(t+2) in flight;
// barrier then guarantees every wave's A(t+1) share is in LDS.
#define GATE2                                                                  \
  do {                                                                         \
    asm volatile("s_waitcnt vmcnt(2)" ::: "memory");                           \
    __builtin_amdgcn_s_barrier();                                              \
  } while (0)

  // prologue: queue [A0(2), B0(4), A1(2)] -> gate leaves A1
  ISSUE_A(0);
  LOAD_B(0, Bc00, Bc01, Bc10, Bc11);
  ISSUE_A(1);
  GATE2;

  // steady state, unroll-2 for static B ping-pong (rule 20).  Invariant at
  // iter top: outstanding = A(tt+1) only; A(tt) in LDS for all waves; B(tt)
  // in the "use" register set.
  for (int tt = 0; tt < NT - 2; tt += 2) {
    LOAD_B(tt + 1, Bn00, Bn01, Bn10, Bn11);
    ISSUE_A(tt + 2);
    READ_A(tt);
    MFMA16(Bc00, Bc01, Bc10, Bc11);
    GATE2;

    LOAD_B(tt + 2, Bc00, Bc01, Bc10, Bc11);
    ISSUE_A(tt + 3);
    READ_A(tt + 1);
    MFMA16(Bn00, Bn01, Bn10, Bn11);
    GATE2;
  }
  // tail: tiles NT-2 (Bc), NT-1 (Bn); A(NT-2),A(NT-1) already issued
  LOAD_B(NT - 1, Bn00, Bn01, Bn10, Bn11);
  READ_A(NT - 2);
  MFMA16(Bc00, Bc01, Bc10, Bc11);
  asm volatile("s_waitcnt vmcnt(0)" ::: "memory");
  __builtin_amdgcn_s_barrier();
  READ_A(NT - 1);
  MFMA16(Bn00, Bn01, Bn10, Bn11);

  // epilogue: C/D col = lane&31, row = (reg&3) + 8*(reg>>2) + 4*hi
  const float alpha = *alpha_p;
#pragma unroll
  for (int mi = 0; mi < 4; ++mi) {
    const int rowt = bm * BM + wm * 128 + mi * 32 + hi * 4;
#pragma unroll
    for (int ni = 0; ni < 2; ++ni) {
      const int col = bn * BN + wn * 64 + ni * 32 + l31;
      const float bv = bias[col];
#pragma unroll
      for (int r = 0; r < 16; ++r) {
        const int row = rowt + (r & 3) + 8 * (r >> 2);
        float v = rintf((float)acc[mi][ni][r] * alpha + bv);
        v = fminf(fmaxf(v, -128.f), 127.f);
        out[(size_t)row * OUT_F + col] = (int)v;
      }
    }
  }
#undef ISSUE_A
#undef LOAD_B
#undef READ_A
#undef MFMA16
#undef GATE2
}

extern "C" void kernel_launch(void* const* d_in, const int* in_sizes, int n_in,
                              void* d_out, int out_size, void* d_ws, size_t ws_size,
                              hipStream_t stream) {
  const int*   x     = (const int*)d_in[0];    // [8192, 4096] int8-valued
  const float* w     = (const float*)d_in[1];  // [4096, 4096] int8-valued
  const float* bias  = (const float*)d_in[2];  // [4096]
  const float* alpha = (const float*)d_in[3];  // scalar
  int* out = (int*)d_out;                      // [8192, 4096] int32 (int8 values)

  int8_t* x8 = (int8_t*)d_ws;                        // 33,554,432 B (packed A)
  int8_t* w8 = x8 + (size_t)ROWS * IN_F;             // 16,777,216 B (packed B)

  static bool attr_done = false;
  if (!attr_done) {
    (void)hipFuncSetAttribute(reinterpret_cast<const void*>(gemm_i8_kernel),
                              hipFuncAttributeMaxDynamicSharedMemorySize,
                              LDS_TOTAL);
    attr_done = true;
  }

  cvt_kernel<<<CVT_BLOCKS, 256, 0, stream>>>((const int4*)x, (const float4*)w,
                                             (int4*)x8, (int4*)w8);

  dim3 grid(OUT_F / BN, ROWS / BM);  // (16, 32) = 512 blocks
  gemm_i8_kernel<<<grid, 512, LDS_TOTAL, stream>>>(x8, w8, bias, alpha, out);
}